// Round 2
// baseline (3785.727 us; speedup 1.0000x reference)
//
#include <hip/hip_runtime.h>
#include <math.h>

#define NN 50000
#define NE 500000
#define NREL 4
#define D 128
#define NB 391            // ceil(NN/128) 128-node dst buckets
#define NBT (NREL * NB)   // 1564
static constexpr float BN_EPS = 1e-5f;

typedef __attribute__((ext_vector_type(8))) short short8;
typedef __attribute__((ext_vector_type(4))) float f32x4;

__device__ __forceinline__ float bf2f(unsigned short u) {
    return __uint_as_float(((unsigned)u) << 16);
}
__device__ __forceinline__ unsigned short f2bf(float f) {  // RTNE
    unsigned x = __float_as_uint(f);
    return (unsigned short)((x + 0x7FFFu + ((x >> 16) & 1u)) >> 16);
}

// ---------------- utility ----------------
__global__ __launch_bounds__(256) void k_zero(int* __restrict__ p, int n) {
    int i = blockIdx.x * blockDim.x + threadIdx.x;
    if (i < n) p[i] = 0;
}

// ---------------- degree count (in-degree per relation) ----------------
__global__ __launch_bounds__(256) void k_count(const int* __restrict__ ei, int* __restrict__ deg) {
    int e = blockIdx.x * blockDim.x + threadIdx.x;
    int r = blockIdx.y;
    if (e < NE) {
        int dst = ei[r * 2 * NE + NE + e];
        atomicAdd(&deg[r * NN + dst], 1);
    }
}

__global__ __launch_bounds__(256) void k_dinv(const int* __restrict__ deg, float* __restrict__ dinv) {
    int i = blockIdx.x * blockDim.x + threadIdx.x;
    int r = blockIdx.y;
    if (i < NN) dinv[r * NN + i] = rsqrtf((float)(deg[r * NN + i] + 1)); // +1 self loop
}

// ---------------- bucket sums ----------------
__global__ __launch_bounds__(256) void k_bsum(const int* __restrict__ deg, int* __restrict__ bsum) {
    int b = blockIdx.x * 256 + threadIdx.x;
    if (b >= NBT) return;
    int r = b / NB, nb = b % NB;
    int n0 = nb * 128, n1 = min(n0 + 128, NN);
    const int* d = deg + r * NN;
    int s = 0;
    for (int n = n0; n < n1; n++) s += d[n];
    bsum[b] = s;
}

// ---------------- bucket offset scan (single block) ----------------
__global__ __launch_bounds__(1024) void k_bscan(const int* __restrict__ bsum, int* __restrict__ boff,
                                                int* __restrict__ bfill) {
    __shared__ int sd[1024];
    __shared__ int carry;
    int tid = threadIdx.x;
    if (tid == 0) carry = 0;
    __syncthreads();
    for (int base = 0; base < NBT; base += 1024) {
        int i = base + tid;
        int v = (i < NBT) ? bsum[i] : 0;
        sd[tid] = v;
        __syncthreads();
        for (int d = 1; d < 1024; d <<= 1) {
            int t = (tid >= d) ? sd[tid - d] : 0;
            __syncthreads();
            sd[tid] += t;
            __syncthreads();
        }
        if (i < NBT) {
            int e = carry + sd[tid] - v;
            boff[i] = e;
            bfill[i] = e;
        }
        __syncthreads();
        if (tid == 1023) carry += sd[1023];
        __syncthreads();
    }
    if (tid == 0) boff[NBT] = carry;
}

// ---------------- bucketed edge scatter: packed = src | dstlocal<<16 ----------------
__global__ __launch_bounds__(256) void k_scatter(const int* __restrict__ ei, int* __restrict__ bfill,
                                                 unsigned* __restrict__ packed) {
    int e = blockIdx.x * 256 + threadIdx.x;
    int r = blockIdx.y;
    if (e >= NE) return;
    int src = ei[r * 2 * NE + e];
    int dst = ei[r * 2 * NE + NE + e];
    int b = r * NB + (dst >> 7);
    int pos = atomicAdd(&bfill[b], 1);
    packed[pos] = (unsigned)src | ((unsigned)(dst & 127) << 16);
}

// ---------------- fp32 -> bf16 cast of x ----------------
__global__ __launch_bounds__(256) void k_cast(const float* __restrict__ x, unsigned short* __restrict__ xb) {
    int i = blockIdx.x * 256 + threadIdx.x;
    if (i * 4 >= NN * D) return;
    float4 v = *(const float4*)(x + (size_t)i * 4);
    unsigned short u[4] = {f2bf(v.x), f2bf(v.y), f2bf(v.z), f2bf(v.w)};
    *(ushort4*)(xb + (size_t)i * 4) = *(ushort4*)u;
}

// ---------------- weight prep: bf16 transposed weights + summed biases ----------------
__global__ __launch_bounds__(256) void k_prep(const float* __restrict__ W1, const float* __restrict__ W2,
                                              const float* __restrict__ l1W, const float* __restrict__ b1,
                                              const float* __restrict__ b2, unsigned short* __restrict__ Wt1,
                                              unsigned short* __restrict__ Wt2, unsigned short* __restrict__ Wt3,
                                              float* __restrict__ bs1, float* __restrict__ bs2) {
    int blk = blockIdx.x, tid = threadIdx.x;
    if (blk < 256) {
        int i = blk * 256 + tid;        // [0, 65536)
        int kk = i & 511, n = i >> 9;   // coalesced stores along kk
        Wt1[n * 512 + kk] = f2bf(W1[kk * 128 + n]);
        Wt2[n * 512 + kk] = f2bf(W2[kk * 128 + n]);
    } else if (blk < 320) {
        int i = (blk - 256) * 256 + tid; // [0, 16384)
        int kk = i & 127, n = i >> 7;
        Wt3[n * 128 + kk] = f2bf(l1W[kk * 128 + n]);
    } else if (tid < 128) {
        bs1[tid] = b1[tid] + b1[128 + tid] + b1[256 + tid] + b1[384 + tid];
        bs2[tid] = b2[tid] + b2[128 + tid] + b2[256 + tid] + b2[384 + tid];
    }
}

// ---------------- bucketed LDS aggregation ----------------
// Acat[n][r*128 + c] = dinv[n] * ( sum_{src->n} in[src][c]*dinv[src] + in[n][c]*dinv[n] )
__global__ __launch_bounds__(512) void k_agg(const unsigned short* __restrict__ in,  // bf16 [NN][128]
                                             const unsigned* __restrict__ packed,
                                             const int* __restrict__ boff,
                                             const float* __restrict__ dinv,         // [NREL][NN]
                                             unsigned short* __restrict__ Acat) {    // bf16 [NN][512]
    __shared__ float acc[128 * 132];  // row stride 132 floats (pad 4) for write-out conflicts
    int tid = threadIdx.x;
    int blk = blockIdx.x;
    int r = blk / NB, nb = blk % NB;
    int n0 = nb * 128;
    int nrows = min(128, NN - n0);
    const float* dv = dinv + r * NN;
    for (int i = tid; i < 128 * 132 / 4; i += 512) ((f32x4*)acc)[i] = (f32x4){0.f, 0.f, 0.f, 0.f};
    __syncthreads();

    int e0 = boff[blk], e1 = boff[blk + 1];
    int w = tid >> 6, lane = tid & 63;
    int tot = e1 - e0;
    int per = (tot + 7) >> 3;
    int es = e0 + w * per;
    int ee = min(es + per, e1);
    const ushort2* in2 = (const ushort2*)in;

    const int PD = 8;  // software pipeline depth over gather latency
    unsigned pk[PD];
    float wk[PD];
    ushort2 uk[PD];
#pragma unroll
    for (int k = 0; k < PD; k++) {
        int e = es + k;
        bool v = e < ee;
        unsigned p = v ? packed[e] : 0u;
        int s = p & 0xFFFF;
        pk[k] = p;
        wk[k] = v ? dv[s] : 0.f;   // sentinel contributes 0
        uk[k] = in2[s * 64 + lane];
    }
    int cnt = ee - es;
    for (int i = 0; i < cnt; i += PD) {
#pragma unroll
        for (int k = 0; k < PD; k++) {
            unsigned p = pk[k];
            float wv = wk[k];
            ushort2 u = uk[k];
            int nl = (p >> 16) & 127;
            float fx = bf2f(u.x) * wv;
            float fy = bf2f(u.y) * wv;
            atomicAdd(&acc[nl * 132 + 2 * lane], fx);      // ds_add_f32, 2-way bank (free)
            atomicAdd(&acc[nl * 132 + 2 * lane + 1], fy);
            int e = es + i + k + PD;
            bool v = e < ee;
            unsigned np = v ? packed[e] : 0u;
            int s = np & 0xFFFF;
            pk[k] = np;
            wk[k] = v ? dv[s] : 0.f;
            uk[k] = in2[s * 64 + lane];
        }
    }
    __syncthreads();

    // self-loop + scale + bf16 write-out (4 threads per row, 32 cols each)
    int nl = tid >> 2, q = tid & 3;
    if (nl < nrows) {
        int n = n0 + nl;
        float wn = dv[n];
        const unsigned short* selfrow = in + (size_t)n * 128;
        unsigned short* orow = Acat + (size_t)n * 512 + r * 128;
#pragma unroll
        for (int c0 = 0; c0 < 32; c0 += 8) {
            int c = q * 32 + c0;
            short8 sv = *(const short8*)(selfrow + c);
            unsigned short ob[8];
#pragma unroll
            for (int j = 0; j < 8; j++) {
                float selfv = bf2f((unsigned short)sv[j]);
                float val = wn * (acc[nl * 132 + c + j] + selfv * wn);
                ob[j] = f2bf(val);
            }
            *(short8*)(orow + c) = *(short8*)ob;
        }
    }
}

// ---------------- MFMA GEMM: C[NN][128] = relu(A[NN][K] @ W[K][128] + bias) (bf16 in/out) ----------------
// Bt is W transposed: Bt[n][k], bf16. STATS: also accumulate per-column sum/sumsq of relu output.
template <int K, bool STATS>
__global__ __launch_bounds__(256) void k_mm(const unsigned short* __restrict__ A,
                                            const unsigned short* __restrict__ Bt,
                                            const float* __restrict__ bias,
                                            unsigned short* __restrict__ C,
                                            float* __restrict__ bnsum) {
    int tid = threadIdx.x;
    int w = tid >> 6, lane = tid & 63;
    int ln = lane & 15, quad = lane >> 4;
    int mwave = blockIdx.x * 256 + w * 64;

    f32x4 acc[4][8];
#pragma unroll
    for (int a = 0; a < 4; a++)
#pragma unroll
        for (int b = 0; b < 8; b++) acc[a][b] = (f32x4){0.f, 0.f, 0.f, 0.f};

    size_t arow[4];
#pragma unroll
    for (int mf = 0; mf < 4; mf++) {
        int m = mwave + mf * 16 + ln;
        arow[mf] = (size_t)min(m, NN - 1) * K;  // clamp; garbage rows guarded at store
    }
    size_t brow[8];
#pragma unroll
    for (int nf = 0; nf < 8; nf++) brow[nf] = (size_t)(nf * 16 + ln) * K;

    for (int k0 = 0; k0 < K; k0 += 32) {
        int kof = k0 + quad * 8;
        short8 af[4], bf[8];
#pragma unroll
        for (int mf = 0; mf < 4; mf++) af[mf] = *(const short8*)(A + arow[mf] + kof);
#pragma unroll
        for (int nf = 0; nf < 8; nf++) bf[nf] = *(const short8*)(Bt + brow[nf] + kof);
#pragma unroll
        for (int mf = 0; mf < 4; mf++)
#pragma unroll
            for (int nf = 0; nf < 8; nf++)
                acc[mf][nf] = __builtin_amdgcn_mfma_f32_16x16x32_bf16(af[mf], bf[nf], acc[mf][nf], 0, 0, 0);
    }

    float bs[8];
#pragma unroll
    for (int nf = 0; nf < 8; nf++) bs[nf] = bias[nf * 16 + ln];
    float sn[8], qn[8];
#pragma unroll
    for (int nf = 0; nf < 8; nf++) { sn[nf] = 0.f; qn[nf] = 0.f; }

#pragma unroll
    for (int mf = 0; mf < 4; mf++)
#pragma unroll
        for (int nf = 0; nf < 8; nf++)
#pragma unroll
            for (int rg = 0; rg < 4; rg++) {
                int m = mwave + mf * 16 + quad * 4 + rg;
                if (m < NN) {
                    float v = fmaxf(acc[mf][nf][rg] + bs[nf], 0.f);
                    if (STATS) { sn[nf] += v; qn[nf] += v * v; }
                    C[(size_t)m * 128 + nf * 16 + ln] = f2bf(v);
                }
            }

    if (STATS) {
#pragma unroll
        for (int nf = 0; nf < 8; nf++) {
            float s = sn[nf], q = qn[nf];
            s += __shfl_xor(s, 16); s += __shfl_xor(s, 32);
            q += __shfl_xor(q, 16); q += __shfl_xor(q, 32);
            if (quad == 0) {
                unsafeAtomicAdd(&bnsum[nf * 16 + ln], s);
                unsafeAtomicAdd(&bnsum[128 + nf * 16 + ln], q);
            }
        }
    }
}

__global__ __launch_bounds__(128) void k_bn_final(const float* __restrict__ sums,
                                                  const float* __restrict__ gamma,
                                                  const float* __restrict__ beta,
                                                  float* __restrict__ bnp) {
    int c = threadIdx.x;
    if (c < D) {
        float mean = sums[c] / (float)NN;
        float var = sums[D + c] / (float)NN - mean * mean;
        float sc = gamma[c] * rsqrtf(var + BN_EPS);
        bnp[c] = sc;
        bnp[D + c] = beta[c] - mean * sc;
    }
}

// ---------------- final: out = relu(BN(R2) @ l1W + l1b) @ l2W + l2b ----------------
__global__ __launch_bounds__(256) void k_final(const unsigned short* __restrict__ R2,
                                               const float* __restrict__ bnp,
                                               const unsigned short* __restrict__ Wt3,
                                               const float* __restrict__ l1b,
                                               const float* __restrict__ l2W,
                                               const float* __restrict__ l2b,
                                               float* __restrict__ out) {
    int tid = threadIdx.x;
    int w = tid >> 6, lane = tid & 63;
    int ln = lane & 15, quad = lane >> 4;
    int mwave = blockIdx.x * 256 + w * 64;

    f32x4 acc[4][8];
#pragma unroll
    for (int a = 0; a < 4; a++)
#pragma unroll
        for (int b = 0; b < 8; b++) acc[a][b] = (f32x4){0.f, 0.f, 0.f, 0.f};

    size_t arow[4];
#pragma unroll
    for (int mf = 0; mf < 4; mf++) {
        int m = mwave + mf * 16 + ln;
        arow[mf] = (size_t)min(m, NN - 1) * 128;
    }
    size_t brow[8];
#pragma unroll
    for (int nf = 0; nf < 8; nf++) brow[nf] = (size_t)(nf * 16 + ln) * 128;

    for (int k0 = 0; k0 < 128; k0 += 32) {
        int kof = k0 + quad * 8;
        float4 scA = *(const float4*)(bnp + kof);
        float4 scB = *(const float4*)(bnp + kof + 4);
        float4 shA = *(const float4*)(bnp + 128 + kof);
        float4 shB = *(const float4*)(bnp + 128 + kof + 4);
        float scv[8] = {scA.x, scA.y, scA.z, scA.w, scB.x, scB.y, scB.z, scB.w};
        float shv[8] = {shA.x, shA.y, shA.z, shA.w, shB.x, shB.y, shB.z, shB.w};
        short8 af[4], bf[8];
#pragma unroll
        for (int mf = 0; mf < 4; mf++) {
            short8 rv = *(const short8*)(R2 + arow[mf] + kof);
            unsigned short ab[8];
#pragma unroll
            for (int j = 0; j < 8; j++)
                ab[j] = f2bf(bf2f((unsigned short)rv[j]) * scv[j] + shv[j]);
            af[mf] = *(short8*)ab;
        }
#pragma unroll
        for (int nf = 0; nf < 8; nf++) bf[nf] = *(const short8*)(Wt3 + brow[nf] + kof);
#pragma unroll
        for (int mf = 0; mf < 4; mf++)
#pragma unroll
            for (int nf = 0; nf < 8; nf++)
                acc[mf][nf] = __builtin_amdgcn_mfma_f32_16x16x32_bf16(af[mf], bf[nf], acc[mf][nf], 0, 0, 0);
    }

    float b1v[8], w0[8], w1[8];
#pragma unroll
    for (int nf = 0; nf < 8; nf++) {
        int n = nf * 16 + ln;
        b1v[nf] = l1b[n];
        w0[nf] = l2W[n * 2];
        w1[nf] = l2W[n * 2 + 1];
    }
    float ob0 = l2b[0], ob1 = l2b[1];
#pragma unroll
    for (int mf = 0; mf < 4; mf++)
#pragma unroll
        for (int rg = 0; rg < 4; rg++) {
            float p0 = 0.f, p1 = 0.f;
#pragma unroll
            for (int nf = 0; nf < 8; nf++) {
                float y = fmaxf(acc[mf][nf][rg] + b1v[nf], 0.f);
                p0 += y * w0[nf];
                p1 += y * w1[nf];
            }
            p0 += __shfl_xor(p0, 1); p0 += __shfl_xor(p0, 2);
            p0 += __shfl_xor(p0, 4); p0 += __shfl_xor(p0, 8);
            p1 += __shfl_xor(p1, 1); p1 += __shfl_xor(p1, 2);
            p1 += __shfl_xor(p1, 4); p1 += __shfl_xor(p1, 8);
            int m = mwave + mf * 16 + quad * 4 + rg;
            if (ln == 0 && m < NN) {
                out[(size_t)m * 2 + 0] = p0 + ob0;
                out[(size_t)m * 2 + 1] = p1 + ob1;
            }
        }
}

extern "C" void kernel_launch(void* const* d_in, const int* in_sizes, int n_in,
                              void* d_out, int out_size, void* d_ws, size_t ws_size,
                              hipStream_t stream) {
    const float* x = (const float*)d_in[0];
    const int* ei = (const int*)d_in[1];
    const float* W1 = (const float*)d_in[2];
    const float* b1 = (const float*)d_in[3];
    const float* W2 = (const float*)d_in[4];
    const float* b2 = (const float*)d_in[5];
    const float* gamma = (const float*)d_in[6];
    const float* beta = (const float*)d_in[7];
    const float* l1W = (const float*)d_in[8];
    const float* l1b = (const float*)d_in[9];
    const float* l2W = (const float*)d_in[10];
    const float* l2b = (const float*)d_in[11];
    float* out = (float*)d_out;

    char* ws = (char*)d_ws;
    size_t off = 0;
    auto alloc = [&](size_t bytes) {
        void* p = ws + off;
        off += (bytes + 255) & ~(size_t)255;
        return p;
    };
    int* deg = (int*)alloc((size_t)NREL * NN * sizeof(int));
    float* dinv = (float*)alloc((size_t)NREL * NN * sizeof(float));
    int* bsum = (int*)alloc(NBT * sizeof(int));
    int* boff = (int*)alloc((NBT + 1) * sizeof(int));
    int* bfill = (int*)alloc(NBT * sizeof(int));
    unsigned* packed = (unsigned*)alloc((size_t)NREL * NE * sizeof(unsigned));       // 8 MB
    unsigned short* xb = (unsigned short*)alloc((size_t)NN * D * 2);                 // 12.8 MB
    unsigned short* Acat = (unsigned short*)alloc((size_t)NN * 512 * 2);             // 51.2 MB
    unsigned short* h1b = (unsigned short*)alloc((size_t)NN * D * 2);                // 12.8 MB
    unsigned short* R2 = (unsigned short*)alloc((size_t)NN * D * 2);                 // 12.8 MB
    unsigned short* Wt1 = (unsigned short*)alloc(128 * 512 * 2);
    unsigned short* Wt2 = (unsigned short*)alloc(128 * 512 * 2);
    unsigned short* Wt3 = (unsigned short*)alloc(128 * 128 * 2);
    float* bs1 = (float*)alloc(128 * sizeof(float));
    float* bs2 = (float*)alloc(128 * sizeof(float));
    float* bnsum = (float*)alloc(256 * sizeof(float));
    float* bnp = (float*)alloc(256 * sizeof(float));

    dim3 egrid((NE + 255) / 256, NREL);
    dim3 ngrid((NN + 255) / 256, NREL);

    k_zero<<<(NREL * NN + 255) / 256, 256, 0, stream>>>(deg, NREL * NN);
    k_zero<<<1, 256, 0, stream>>>((int*)bnsum, 256);
    k_prep<<<321, 256, 0, stream>>>(W1, W2, l1W, b1, b2, Wt1, Wt2, Wt3, bs1, bs2);
    k_cast<<<(NN * D / 4 + 255) / 256, 256, 0, stream>>>(x, xb);
    k_count<<<egrid, 256, 0, stream>>>(ei, deg);
    k_dinv<<<ngrid, 256, 0, stream>>>(deg, dinv);
    k_bsum<<<(NBT + 255) / 256, 256, 0, stream>>>(deg, bsum);
    k_bscan<<<1, 1024, 0, stream>>>(bsum, boff, bfill);
    k_scatter<<<egrid, 256, 0, stream>>>(ei, bfill, packed);

    // layer 1: aggregate x per relation -> Acat, then one K=512 GEMM
    k_agg<<<NBT, 512, 0, stream>>>(xb, packed, boff, dinv, Acat);
    k_mm<512, false><<<(NN + 255) / 256, 256, 0, stream>>>(Acat, Wt1, bs1, h1b, nullptr);
    // layer 2
    k_agg<<<NBT, 512, 0, stream>>>(h1b, packed, boff, dinv, Acat);
    k_mm<512, true><<<(NN + 255) / 256, 256, 0, stream>>>(Acat, Wt2, bs2, R2, bnsum);
    // BN params + fused MLP head
    k_bn_final<<<1, 128, 0, stream>>>(bnsum, gamma, beta, bnp);
    k_final<<<(NN + 255) / 256, 256, 0, stream>>>(R2, bnp, Wt3, l1b, l2W, l2b, out);
}

// Round 3
// 1191.120 us; speedup vs baseline: 3.1783x; 3.1783x over previous
//
#include <hip/hip_runtime.h>
#include <math.h>

#define NN 50000
#define NE 500000
#define NREL 4
#define D 128
#define NB 391            // ceil(NN/128) 128-node dst buckets
#define NBT (NREL * NB)   // 1564
static constexpr float BN_EPS = 1e-5f;

typedef __attribute__((ext_vector_type(8))) short short8;
typedef __attribute__((ext_vector_type(4))) float f32x4;

__device__ __forceinline__ float bf2f(unsigned short u) {
    return __uint_as_float(((unsigned)u) << 16);
}
__device__ __forceinline__ unsigned short f2bf(float f) {  // RTNE
    unsigned x = __float_as_uint(f);
    return (unsigned short)((x + 0x7FFFu + ((x >> 16) & 1u)) >> 16);
}

// ---------------- utility ----------------
__global__ __launch_bounds__(256) void k_zero(int* __restrict__ p, int n) {
    int i = blockIdx.x * blockDim.x + threadIdx.x;
    if (i < n) p[i] = 0;
}

// ---------------- degree count (in-degree per relation) ----------------
__global__ __launch_bounds__(256) void k_count(const int* __restrict__ ei, int* __restrict__ deg) {
    int e = blockIdx.x * blockDim.x + threadIdx.x;
    int r = blockIdx.y;
    if (e < NE) {
        int dst = ei[r * 2 * NE + NE + e];
        atomicAdd(&deg[r * NN + dst], 1);
    }
}

__global__ __launch_bounds__(256) void k_dinv(const int* __restrict__ deg, float* __restrict__ dinv) {
    int i = blockIdx.x * blockDim.x + threadIdx.x;
    int r = blockIdx.y;
    if (i < NN) dinv[r * NN + i] = rsqrtf((float)(deg[r * NN + i] + 1)); // +1 self loop
}

// ---------------- per-bucket edge count (block reduce) ----------------
__global__ __launch_bounds__(128) void k_bsum(const int* __restrict__ deg, int* __restrict__ bsum) {
    int blk = blockIdx.x;  // 0..NBT-1
    int r = blk / NB, nb = blk % NB;
    int n0 = nb * 128;
    int nrows = min(128, NN - n0);
    int tid = threadIdx.x;
    __shared__ int sd[128];
    sd[tid] = (tid < nrows) ? deg[r * NN + n0 + tid] : 0;
    __syncthreads();
    for (int off = 64; off > 0; off >>= 1) {
        if (tid < off) sd[tid] += sd[tid + off];
        __syncthreads();
    }
    if (tid == 0) bsum[blk] = sd[0];
}

// ---------------- bucket offset scan (single block) ----------------
__global__ __launch_bounds__(1024) void k_bscan(const int* __restrict__ bsum, int* __restrict__ boff,
                                                int* __restrict__ bfill) {
    __shared__ int sd[1024];
    __shared__ int carry;
    int tid = threadIdx.x;
    if (tid == 0) carry = 0;
    __syncthreads();
    for (int base = 0; base < NBT; base += 1024) {
        int i = base + tid;
        int v = (i < NBT) ? bsum[i] : 0;
        sd[tid] = v;
        __syncthreads();
        for (int d = 1; d < 1024; d <<= 1) {
            int t = (tid >= d) ? sd[tid - d] : 0;
            __syncthreads();
            sd[tid] += t;
            __syncthreads();
        }
        if (i < NBT) {
            int e = carry + sd[tid] - v;
            boff[i] = e;
            bfill[i] = e;
        }
        __syncthreads();
        if (tid == 1023) carry += sd[1023];
        __syncthreads();
    }
    if (tid == 0) boff[NBT] = carry;
}

// ---------------- bucketed edge scatter: packed = src | dstlocal<<16 ----------------
__global__ __launch_bounds__(256) void k_scatter(const int* __restrict__ ei, int* __restrict__ bfill,
                                                 unsigned* __restrict__ packed) {
    int e = blockIdx.x * 256 + threadIdx.x;
    int r = blockIdx.y;
    if (e >= NE) return;
    int src = ei[r * 2 * NE + e];
    int dst = ei[r * 2 * NE + NE + e];
    int b = r * NB + (dst >> 7);
    int pos = atomicAdd(&bfill[b], 1);
    packed[pos] = (unsigned)src | ((unsigned)(dst & 127) << 16);
}

// ---------------- per-bucket sort into CSR + rowp ----------------
__global__ __launch_bounds__(256) void k_sort(const int* __restrict__ deg, const int* __restrict__ boff,
                                              const unsigned* __restrict__ packed,
                                              int* __restrict__ rowp, unsigned short* __restrict__ csr) {
    int blk = blockIdx.x;  // 0..NBT-1
    int r = blk / NB, nb = blk % NB;
    int n0 = nb * 128;
    int nrows = min(128, NN - n0);
    int tid = threadIdx.x;
    __shared__ int sd[128];
    __shared__ int cnt[128];
    int orig = 0;
    if (tid < 128) {
        orig = (tid < nrows) ? deg[r * NN + n0 + tid] : 0;
        sd[tid] = orig;
        cnt[tid] = 0;
    }
    __syncthreads();
    // Hillis-Steele inclusive scan over 128
    for (int d = 1; d < 128; d <<= 1) {
        int t = 0;
        if (tid < 128 && tid >= d) t = sd[tid - d];
        __syncthreads();
        if (tid < 128) sd[tid] += t;
        __syncthreads();
    }
    int base = boff[blk];
    int excl = 0;
    if (tid < 128) excl = sd[tid] - orig;
    __syncthreads();
    if (tid < 128) sd[tid] = excl;  // now sd = exclusive offsets
    if (tid < nrows) rowp[r * (NN + 1) + n0 + tid] = base + excl;
    if (nb == NB - 1 && tid == 0) rowp[r * (NN + 1) + NN] = boff[r * NB + NB];
    __syncthreads();
    int e0 = boff[blk], e1 = boff[blk + 1];
    for (int e = e0 + tid; e < e1; e += 256) {
        unsigned p = packed[e];
        int s = p & 0xFFFF;
        int dl = (p >> 16) & 127;
        int pos = atomicAdd(&cnt[dl], 1);
        csr[base + sd[dl] + pos] = (unsigned short)s;
    }
}

// ---------------- fp32 -> bf16 cast of x ----------------
__global__ __launch_bounds__(256) void k_cast(const float* __restrict__ x, unsigned short* __restrict__ xb) {
    int i = blockIdx.x * 256 + threadIdx.x;
    if (i * 4 >= NN * D) return;
    float4 v = *(const float4*)(x + (size_t)i * 4);
    unsigned short u[4] = {f2bf(v.x), f2bf(v.y), f2bf(v.z), f2bf(v.w)};
    *(ushort4*)(xb + (size_t)i * 4) = *(ushort4*)u;
}

// ---------------- weight prep: bf16 transposed weights + summed biases ----------------
__global__ __launch_bounds__(256) void k_prep(const float* __restrict__ W1, const float* __restrict__ W2,
                                              const float* __restrict__ l1W, const float* __restrict__ b1,
                                              const float* __restrict__ b2, unsigned short* __restrict__ Wt1,
                                              unsigned short* __restrict__ Wt2, unsigned short* __restrict__ Wt3,
                                              float* __restrict__ bs1, float* __restrict__ bs2) {
    int blk = blockIdx.x, tid = threadIdx.x;
    if (blk < 256) {
        int i = blk * 256 + tid;        // [0, 65536)
        int kk = i & 511, n = i >> 9;   // coalesced stores along kk
        Wt1[n * 512 + kk] = f2bf(W1[kk * 128 + n]);
        Wt2[n * 512 + kk] = f2bf(W2[kk * 128 + n]);
    } else if (blk < 320) {
        int i = (blk - 256) * 256 + tid; // [0, 16384)
        int kk = i & 127, n = i >> 7;
        Wt3[n * 128 + kk] = f2bf(l1W[kk * 128 + n]);
    } else if (tid < 128) {
        bs1[tid] = b1[tid] + b1[128 + tid] + b1[256 + tid] + b1[384 + tid];
        bs2[tid] = b2[tid] + b2[128 + tid] + b2[256 + tid] + b2[384 + tid];
    }
}

// ---------------- per-(node,relation) gather aggregation ----------------
// Acat[n][r*128+c] = dinv[n] * ( sum_{src->n} in[src][c]*dinv[src] + in[n][c]*dinv[n] )
__global__ __launch_bounds__(256) void k_agg(const unsigned short* __restrict__ in,  // bf16 [NN][128]
                                             const unsigned short* __restrict__ csr,
                                             const int* __restrict__ rowp_all,
                                             const float* __restrict__ dinv,         // [NREL][NN]
                                             unsigned short* __restrict__ Acat) {    // bf16 [NN][512]
    int r = blockIdx.y;
    int wave = threadIdx.x >> 6, lane = threadIdx.x & 63;
    int n = blockIdx.x * 4 + wave;
    if (n >= NN) return;
    const int* rowp = rowp_all + r * (NN + 1);
    const float* dv = dinv + r * NN;
    int start = rowp[n], end = rowp[n + 1];
    const ushort2* in2 = (const ushort2*)in;
    float ax = 0.f, ay = 0.f;
    for (int e = start; e < end; e++) {
        int s = csr[e];
        float w = dv[s];
        ushort2 u = in2[s * 64 + lane];
        ax = fmaf(bf2f(u.x), w, ax);
        ay = fmaf(bf2f(u.y), w, ay);
    }
    float wn = dv[n];
    ushort2 us = in2[n * 64 + lane];
    ax = fmaf(bf2f(us.x), wn, ax);
    ay = fmaf(bf2f(us.y), wn, ay);
    ushort2 o;
    o.x = f2bf(wn * ax);
    o.y = f2bf(wn * ay);
    *(ushort2*)(Acat + (size_t)n * 512 + r * 128 + 2 * lane) = o;
}

// ---------------- MFMA GEMM: C[NN][128] = relu(A[NN][K] @ W[K][128] + bias) (bf16 in/out) ----------------
template <int K, bool STATS>
__global__ __launch_bounds__(256) void k_mm(const unsigned short* __restrict__ A,
                                            const unsigned short* __restrict__ Bt,
                                            const float* __restrict__ bias,
                                            unsigned short* __restrict__ C,
                                            float* __restrict__ bnsum) {
    int tid = threadIdx.x;
    int w = tid >> 6, lane = tid & 63;
    int ln = lane & 15, quad = lane >> 4;
    int mwave = blockIdx.x * 256 + w * 64;

    f32x4 acc[4][8];
#pragma unroll
    for (int a = 0; a < 4; a++)
#pragma unroll
        for (int b = 0; b < 8; b++) acc[a][b] = (f32x4){0.f, 0.f, 0.f, 0.f};

    size_t arow[4];
#pragma unroll
    for (int mf = 0; mf < 4; mf++) {
        int m = mwave + mf * 16 + ln;
        arow[mf] = (size_t)min(m, NN - 1) * K;  // clamp; garbage rows guarded at store
    }
    size_t brow[8];
#pragma unroll
    for (int nf = 0; nf < 8; nf++) brow[nf] = (size_t)(nf * 16 + ln) * K;

    for (int k0 = 0; k0 < K; k0 += 32) {
        int kof = k0 + quad * 8;
        short8 af[4], bf[8];
#pragma unroll
        for (int mf = 0; mf < 4; mf++) af[mf] = *(const short8*)(A + arow[mf] + kof);
#pragma unroll
        for (int nf = 0; nf < 8; nf++) bf[nf] = *(const short8*)(Bt + brow[nf] + kof);
#pragma unroll
        for (int mf = 0; mf < 4; mf++)
#pragma unroll
            for (int nf = 0; nf < 8; nf++)
                acc[mf][nf] = __builtin_amdgcn_mfma_f32_16x16x32_bf16(af[mf], bf[nf], acc[mf][nf], 0, 0, 0);
    }

    float bs[8];
#pragma unroll
    for (int nf = 0; nf < 8; nf++) bs[nf] = bias[nf * 16 + ln];
    float sn[8], qn[8];
#pragma unroll
    for (int nf = 0; nf < 8; nf++) { sn[nf] = 0.f; qn[nf] = 0.f; }

#pragma unroll
    for (int mf = 0; mf < 4; mf++)
#pragma unroll
        for (int nf = 0; nf < 8; nf++)
#pragma unroll
            for (int rg = 0; rg < 4; rg++) {
                int m = mwave + mf * 16 + quad * 4 + rg;
                if (m < NN) {
                    float v = fmaxf(acc[mf][nf][rg] + bs[nf], 0.f);
                    if (STATS) { sn[nf] += v; qn[nf] += v * v; }
                    C[(size_t)m * 128 + nf * 16 + ln] = f2bf(v);
                }
            }

    if (STATS) {
#pragma unroll
        for (int nf = 0; nf < 8; nf++) {
            float s = sn[nf], q = qn[nf];
            s += __shfl_xor(s, 16); s += __shfl_xor(s, 32);
            q += __shfl_xor(q, 16); q += __shfl_xor(q, 32);
            if (quad == 0) {
                unsafeAtomicAdd(&bnsum[nf * 16 + ln], s);
                unsafeAtomicAdd(&bnsum[128 + nf * 16 + ln], q);
            }
        }
    }
}

__global__ __launch_bounds__(128) void k_bn_final(const float* __restrict__ sums,
                                                  const float* __restrict__ gamma,
                                                  const float* __restrict__ beta,
                                                  float* __restrict__ bnp) {
    int c = threadIdx.x;
    if (c < D) {
        float mean = sums[c] / (float)NN;
        float var = sums[D + c] / (float)NN - mean * mean;
        float sc = gamma[c] * rsqrtf(var + BN_EPS);
        bnp[c] = sc;
        bnp[D + c] = beta[c] - mean * sc;
    }
}

// ---------------- final: out = relu(BN(R2) @ l1W + l1b) @ l2W + l2b ----------------
__global__ __launch_bounds__(256) void k_final(const unsigned short* __restrict__ R2,
                                               const float* __restrict__ bnp,
                                               const unsigned short* __restrict__ Wt3,
                                               const float* __restrict__ l1b,
                                               const float* __restrict__ l2W,
                                               const float* __restrict__ l2b,
                                               float* __restrict__ out) {
    int tid = threadIdx.x;
    int w = tid >> 6, lane = tid & 63;
    int ln = lane & 15, quad = lane >> 4;
    int mwave = blockIdx.x * 256 + w * 64;

    f32x4 acc[4][8];
#pragma unroll
    for (int a = 0; a < 4; a++)
#pragma unroll
        for (int b = 0; b < 8; b++) acc[a][b] = (f32x4){0.f, 0.f, 0.f, 0.f};

    size_t arow[4];
#pragma unroll
    for (int mf = 0; mf < 4; mf++) {
        int m = mwave + mf * 16 + ln;
        arow[mf] = (size_t)min(m, NN - 1) * 128;
    }
    size_t brow[8];
#pragma unroll
    for (int nf = 0; nf < 8; nf++) brow[nf] = (size_t)(nf * 16 + ln) * 128;

    for (int k0 = 0; k0 < 128; k0 += 32) {
        int kof = k0 + quad * 8;
        float4 scA = *(const float4*)(bnp + kof);
        float4 scB = *(const float4*)(bnp + kof + 4);
        float4 shA = *(const float4*)(bnp + 128 + kof);
        float4 shB = *(const float4*)(bnp + 128 + kof + 4);
        float scv[8] = {scA.x, scA.y, scA.z, scA.w, scB.x, scB.y, scB.z, scB.w};
        float shv[8] = {shA.x, shA.y, shA.z, shA.w, shB.x, shB.y, shB.z, shB.w};
        short8 af[4], bf[8];
#pragma unroll
        for (int mf = 0; mf < 4; mf++) {
            short8 rv = *(const short8*)(R2 + arow[mf] + kof);
            unsigned short ab[8];
#pragma unroll
            for (int j = 0; j < 8; j++)
                ab[j] = f2bf(bf2f((unsigned short)rv[j]) * scv[j] + shv[j]);
            af[mf] = *(short8*)ab;
        }
#pragma unroll
        for (int nf = 0; nf < 8; nf++) bf[nf] = *(const short8*)(Wt3 + brow[nf] + kof);
#pragma unroll
        for (int mf = 0; mf < 4; mf++)
#pragma unroll
            for (int nf = 0; nf < 8; nf++)
                acc[mf][nf] = __builtin_amdgcn_mfma_f32_16x16x32_bf16(af[mf], bf[nf], acc[mf][nf], 0, 0, 0);
    }

    float b1v[8], w0[8], w1[8];
#pragma unroll
    for (int nf = 0; nf < 8; nf++) {
        int n = nf * 16 + ln;
        b1v[nf] = l1b[n];
        w0[nf] = l2W[n * 2];
        w1[nf] = l2W[n * 2 + 1];
    }
    float ob0 = l2b[0], ob1 = l2b[1];
#pragma unroll
    for (int mf = 0; mf < 4; mf++)
#pragma unroll
        for (int rg = 0; rg < 4; rg++) {
            float p0 = 0.f, p1 = 0.f;
#pragma unroll
            for (int nf = 0; nf < 8; nf++) {
                float y = fmaxf(acc[mf][nf][rg] + b1v[nf], 0.f);
                p0 += y * w0[nf];
                p1 += y * w1[nf];
            }
            p0 += __shfl_xor(p0, 1); p0 += __shfl_xor(p0, 2);
            p0 += __shfl_xor(p0, 4); p0 += __shfl_xor(p0, 8);
            p1 += __shfl_xor(p1, 1); p1 += __shfl_xor(p1, 2);
            p1 += __shfl_xor(p1, 4); p1 += __shfl_xor(p1, 8);
            int m = mwave + mf * 16 + quad * 4 + rg;
            if (ln == 0 && m < NN) {
                out[(size_t)m * 2 + 0] = p0 + ob0;
                out[(size_t)m * 2 + 1] = p1 + ob1;
            }
        }
}

extern "C" void kernel_launch(void* const* d_in, const int* in_sizes, int n_in,
                              void* d_out, int out_size, void* d_ws, size_t ws_size,
                              hipStream_t stream) {
    const float* x = (const float*)d_in[0];
    const int* ei = (const int*)d_in[1];
    const float* W1 = (const float*)d_in[2];
    const float* b1 = (const float*)d_in[3];
    const float* W2 = (const float*)d_in[4];
    const float* b2 = (const float*)d_in[5];
    const float* gamma = (const float*)d_in[6];
    const float* beta = (const float*)d_in[7];
    const float* l1W = (const float*)d_in[8];
    const float* l1b = (const float*)d_in[9];
    const float* l2W = (const float*)d_in[10];
    const float* l2b = (const float*)d_in[11];
    float* out = (float*)d_out;

    char* ws = (char*)d_ws;
    size_t off = 0;
    auto alloc = [&](size_t bytes) {
        void* p = ws + off;
        off += (bytes + 255) & ~(size_t)255;
        return p;
    };
    int* deg = (int*)alloc((size_t)NREL * NN * sizeof(int));
    float* dinv = (float*)alloc((size_t)NREL * NN * sizeof(float));
    int* bsum = (int*)alloc(NBT * sizeof(int));
    int* boff = (int*)alloc((NBT + 1) * sizeof(int));
    int* bfill = (int*)alloc(NBT * sizeof(int));
    int* rowp = (int*)alloc((size_t)NREL * (NN + 1) * sizeof(int));
    unsigned* packed = (unsigned*)alloc((size_t)NREL * NE * sizeof(unsigned));       // 8 MB
    unsigned short* csr = (unsigned short*)alloc((size_t)NREL * NE * 2);             // 4 MB
    unsigned short* xb = (unsigned short*)alloc((size_t)NN * D * 2);                 // 12.8 MB
    unsigned short* Acat = (unsigned short*)alloc((size_t)NN * 512 * 2);             // 51.2 MB
    unsigned short* h1b = (unsigned short*)alloc((size_t)NN * D * 2);                // 12.8 MB
    unsigned short* R2b = (unsigned short*)alloc((size_t)NN * D * 2);                // 12.8 MB
    unsigned short* Wt1 = (unsigned short*)alloc(128 * 512 * 2);
    unsigned short* Wt2 = (unsigned short*)alloc(128 * 512 * 2);
    unsigned short* Wt3 = (unsigned short*)alloc(128 * 128 * 2);
    float* bs1 = (float*)alloc(128 * sizeof(float));
    float* bs2 = (float*)alloc(128 * sizeof(float));
    float* bnsum = (float*)alloc(256 * sizeof(float));
    float* bnp = (float*)alloc(256 * sizeof(float));

    dim3 egrid((NE + 255) / 256, NREL);
    dim3 ngrid((NN + 255) / 256, NREL);

    k_zero<<<(NREL * NN + 255) / 256, 256, 0, stream>>>(deg, NREL * NN);
    k_zero<<<1, 256, 0, stream>>>((int*)bnsum, 256);
    k_prep<<<321, 256, 0, stream>>>(W1, W2, l1W, b1, b2, Wt1, Wt2, Wt3, bs1, bs2);
    k_cast<<<(NN * D / 4 + 255) / 256, 256, 0, stream>>>(x, xb);
    k_count<<<egrid, 256, 0, stream>>>(ei, deg);
    k_dinv<<<ngrid, 256, 0, stream>>>(deg, dinv);
    k_bsum<<<NBT, 128, 0, stream>>>(deg, bsum);
    k_bscan<<<1, 1024, 0, stream>>>(bsum, boff, bfill);
    k_scatter<<<egrid, 256, 0, stream>>>(ei, bfill, packed);
    k_sort<<<NBT, 256, 0, stream>>>(deg, boff, packed, rowp, csr);

    dim3 agrid((NN + 3) / 4, NREL);
    // layer 1: aggregate x per relation -> Acat (concat), then one K=512 GEMM
    k_agg<<<agrid, 256, 0, stream>>>(xb, csr, rowp, dinv, Acat);
    k_mm<512, false><<<(NN + 255) / 256, 256, 0, stream>>>(Acat, Wt1, bs1, h1b, nullptr);
    // layer 2
    k_agg<<<agrid, 256, 0, stream>>>(h1b, csr, rowp, dinv, Acat);
    k_mm<512, true><<<(NN + 255) / 256, 256, 0, stream>>>(Acat, Wt2, bs2, R2b, bnsum);
    // BN params + fused MLP head
    k_bn_final<<<1, 128, 0, stream>>>(bnsum, gamma, beta, bnp);
    k_final<<<(NN + 255) / 256, 256, 0, stream>>>(R2b, bnp, Wt3, l1b, l2W, l2b, out);
}

// Round 4
// 622.972 us; speedup vs baseline: 6.0769x; 1.9120x over previous
//
#include <hip/hip_runtime.h>
#include <math.h>

#define NN 50000
#define NE 500000
#define NREL 4
#define D 128
#define RSZ 512                 // dst-range size per build block
#define NRANGE 98               // ceil(NN/512)
#define NBK (NREL * NRANGE)     // 392 build blocks
#define BCAP 6144               // per-bucket csr capacity (mean 5120, sigma 71 -> +14 sigma)
static constexpr float BN_EPS = 1e-5f;

typedef __attribute__((ext_vector_type(8))) short short8;
typedef __attribute__((ext_vector_type(4))) float f32x4;

__device__ __forceinline__ float bf2f(unsigned short u) {
    return __uint_as_float(((unsigned)u) << 16);
}
__device__ __forceinline__ unsigned short f2bf(float f) {  // RTNE
    unsigned x = __float_as_uint(f);
    return (unsigned short)((x + 0x7FFFu + ((x >> 16) & 1u)) >> 16);
}

// ---------------- utility ----------------
__global__ __launch_bounds__(256) void k_zero(int* __restrict__ p, int n) {
    int i = blockIdx.x * blockDim.x + threadIdx.x;
    if (i < n) p[i] = 0;
}

// ---------------- fused graph build: one block per (relation, 512-node dst range) ----------
// Streams the relation's dst array; keeps in-range edges in LDS; counting-sorts into a
// block-private fixed-capacity csr window. Emits csr (ushort src), rstart/rend, dinv.
// No global atomics, all global writes coalesced & block-private.
__global__ __launch_bounds__(512) void k_build(const int* __restrict__ ei,
                                               unsigned short* __restrict__ csr,
                                               int* __restrict__ rstart,
                                               int* __restrict__ rend,
                                               float* __restrict__ dinv) {
    int blk = blockIdx.x;  // r * NRANGE + q
    int r = blk / NRANGE, q = blk % NRANGE;
    int n0 = q * RSZ;
    int nrows = min(RSZ, NN - n0);
    const int* srcp = ei + r * 2 * NE;
    const int* dstp = srcp + NE;
    __shared__ int stage[BCAP];          // src | dstlocal<<16
    __shared__ unsigned short csr_s[BCAP];
    __shared__ int hist[RSZ], off[RSZ], cnt[RSZ];
    __shared__ int nedge;
    int tid = threadIdx.x;
    if (tid == 0) nedge = 0;
    hist[tid] = 0;
    cnt[tid] = 0;
    __syncthreads();
    // single pass over dst stream (int4); collect in-range edges into LDS
    for (int e4 = tid; e4 < NE / 4; e4 += 512) {
        int4 d4 = ((const int4*)dstp)[e4];
        int dd[4] = {d4.x, d4.y, d4.z, d4.w};
#pragma unroll
        for (int j = 0; j < 4; j++) {
            int d = dd[j];
            if ((d >> 9) == q) {
                int s = srcp[e4 * 4 + j];
                int p = atomicAdd(&nedge, 1);
                stage[p] = s | ((d & 511) << 16);
            }
        }
    }
    __syncthreads();
    int tot = nedge;
    // histogram over dst-local
    for (int i = tid; i < tot; i += 512) atomicAdd(&hist[stage[i] >> 16], 1);
    __syncthreads();
    int h = hist[tid];
    if (tid < nrows) dinv[r * NN + n0 + tid] = rsqrtf((float)(h + 1));  // +1 self loop
    // Hillis-Steele inclusive scan -> exclusive offsets
    off[tid] = h;
    __syncthreads();
    for (int dstep = 1; dstep < 512; dstep <<= 1) {
        int t = (tid >= dstep) ? off[tid - dstep] : 0;
        __syncthreads();
        off[tid] += t;
        __syncthreads();
    }
    int excl = off[tid] - h;
    __syncthreads();
    off[tid] = excl;
    int base = blk * BCAP;
    if (tid < nrows) {
        rstart[r * NN + n0 + tid] = base + excl;
        rend[r * NN + n0 + tid] = base + excl + h;
    }
    __syncthreads();
    // counting-sort placement into LDS staging
    for (int i = tid; i < tot; i += 512) {
        int v = stage[i];
        int dl = v >> 16;
        int p = atomicAdd(&cnt[dl], 1);
        csr_s[off[dl] + p] = (unsigned short)(v & 0xFFFF);
    }
    __syncthreads();
    // coalesced block-private write-out
    for (int i = tid; i < tot; i += 512) csr[base + i] = csr_s[i];
}

// ---------------- fp32 -> bf16 cast of x ----------------
__global__ __launch_bounds__(256) void k_cast(const float* __restrict__ x, unsigned short* __restrict__ xb) {
    int i = blockIdx.x * 256 + threadIdx.x;
    if (i * 4 >= NN * D) return;
    float4 v = *(const float4*)(x + (size_t)i * 4);
    unsigned short u[4] = {f2bf(v.x), f2bf(v.y), f2bf(v.z), f2bf(v.w)};
    *(ushort4*)(xb + (size_t)i * 4) = *(ushort4*)u;
}

// ---------------- weight prep: bf16 transposed weights + summed biases ----------------
__global__ __launch_bounds__(256) void k_prep(const float* __restrict__ W1, const float* __restrict__ W2,
                                              const float* __restrict__ l1W, const float* __restrict__ b1,
                                              const float* __restrict__ b2, unsigned short* __restrict__ Wt1,
                                              unsigned short* __restrict__ Wt2, unsigned short* __restrict__ Wt3,
                                              float* __restrict__ bs1, float* __restrict__ bs2) {
    int blk = blockIdx.x, tid = threadIdx.x;
    if (blk < 256) {
        int i = blk * 256 + tid;         // [0, 65536)
        int kk = i & 511, n = i >> 9;    // coalesced stores along kk
        Wt1[n * 512 + kk] = f2bf(W1[kk * 128 + n]);
        Wt2[n * 512 + kk] = f2bf(W2[kk * 128 + n]);
    } else if (blk < 320) {
        int i = (blk - 256) * 256 + tid; // [0, 16384)
        int kk = i & 127, n = i >> 7;
        Wt3[n * 128 + kk] = f2bf(l1W[kk * 128 + n]);
    } else if (tid < 128) {
        bs1[tid] = b1[tid] + b1[128 + tid] + b1[256 + tid] + b1[384 + tid];
        bs2[tid] = b2[tid] + b2[128 + tid] + b2[256 + tid] + b2[384 + tid];
    }
}

// ---------------- per-(node,relation) gather aggregation, 4-way unrolled ----------------
// Acat[n][r*128+c] = dinv[n] * ( sum_{src->n} in[src][c]*dinv[src] + in[n][c]*dinv[n] )
__global__ __launch_bounds__(256) void k_agg(const unsigned short* __restrict__ in,  // bf16 [NN][128]
                                             const unsigned short* __restrict__ csr,
                                             const int* __restrict__ rstart,
                                             const int* __restrict__ rend,
                                             const float* __restrict__ dinv,         // [NREL][NN]
                                             unsigned short* __restrict__ Acat) {    // bf16 [NN][512]
    int r = blockIdx.y;
    int wave = threadIdx.x >> 6, lane = threadIdx.x & 63;
    int n = blockIdx.x * 4 + wave;
    if (n >= NN) return;
    const float* dv = dinv + r * NN;
    int start = rstart[r * NN + n], end = rend[r * NN + n];
    const ushort2* in2 = (const ushort2*)in;
    float ax = 0.f, ay = 0.f;
    int e = start;
    for (; e + 4 <= end; e += 4) {
        int s0 = csr[e], s1 = csr[e + 1], s2 = csr[e + 2], s3 = csr[e + 3];
        float w0 = dv[s0], w1 = dv[s1], w2 = dv[s2], w3 = dv[s3];
        ushort2 u0 = in2[s0 * 64 + lane];
        ushort2 u1 = in2[s1 * 64 + lane];
        ushort2 u2 = in2[s2 * 64 + lane];
        ushort2 u3 = in2[s3 * 64 + lane];
        ax = fmaf(bf2f(u0.x), w0, ax); ay = fmaf(bf2f(u0.y), w0, ay);
        ax = fmaf(bf2f(u1.x), w1, ax); ay = fmaf(bf2f(u1.y), w1, ay);
        ax = fmaf(bf2f(u2.x), w2, ax); ay = fmaf(bf2f(u2.y), w2, ay);
        ax = fmaf(bf2f(u3.x), w3, ax); ay = fmaf(bf2f(u3.y), w3, ay);
    }
    for (; e < end; e++) {
        int s = csr[e];
        float w = dv[s];
        ushort2 u = in2[s * 64 + lane];
        ax = fmaf(bf2f(u.x), w, ax);
        ay = fmaf(bf2f(u.y), w, ay);
    }
    float wn = dv[n];
    ushort2 us = in2[n * 64 + lane];
    ax = fmaf(bf2f(us.x), wn, ax);
    ay = fmaf(bf2f(us.y), wn, ay);
    ushort2 o;
    o.x = f2bf(wn * ax);
    o.y = f2bf(wn * ay);
    *(ushort2*)(Acat + (size_t)n * 512 + r * 128 + 2 * lane) = o;
}

// ---------------- MFMA GEMM: C[NN][128] = relu(A[NN][K] @ W[K][128] + bias) (bf16 in/out) ----------------
template <int K, bool STATS>
__global__ __launch_bounds__(256) void k_mm(const unsigned short* __restrict__ A,
                                            const unsigned short* __restrict__ Bt,
                                            const float* __restrict__ bias,
                                            unsigned short* __restrict__ C,
                                            float* __restrict__ bnsum) {
    int tid = threadIdx.x;
    int w = tid >> 6, lane = tid & 63;
    int ln = lane & 15, quad = lane >> 4;
    int mwave = blockIdx.x * 256 + w * 64;

    f32x4 acc[4][8];
#pragma unroll
    for (int a = 0; a < 4; a++)
#pragma unroll
        for (int b = 0; b < 8; b++) acc[a][b] = (f32x4){0.f, 0.f, 0.f, 0.f};

    size_t arow[4];
#pragma unroll
    for (int mf = 0; mf < 4; mf++) {
        int m = mwave + mf * 16 + ln;
        arow[mf] = (size_t)min(m, NN - 1) * K;  // clamp; garbage rows guarded at store
    }
    size_t brow[8];
#pragma unroll
    for (int nf = 0; nf < 8; nf++) brow[nf] = (size_t)(nf * 16 + ln) * K;

    for (int k0 = 0; k0 < K; k0 += 32) {
        int kof = k0 + quad * 8;
        short8 af[4], bf[8];
#pragma unroll
        for (int mf = 0; mf < 4; mf++) af[mf] = *(const short8*)(A + arow[mf] + kof);
#pragma unroll
        for (int nf = 0; nf < 8; nf++) bf[nf] = *(const short8*)(Bt + brow[nf] + kof);
#pragma unroll
        for (int mf = 0; mf < 4; mf++)
#pragma unroll
            for (int nf = 0; nf < 8; nf++)
                acc[mf][nf] = __builtin_amdgcn_mfma_f32_16x16x32_bf16(af[mf], bf[nf], acc[mf][nf], 0, 0, 0);
    }

    float bs[8];
#pragma unroll
    for (int nf = 0; nf < 8; nf++) bs[nf] = bias[nf * 16 + ln];
    float sn[8], qn[8];
#pragma unroll
    for (int nf = 0; nf < 8; nf++) { sn[nf] = 0.f; qn[nf] = 0.f; }

#pragma unroll
    for (int mf = 0; mf < 4; mf++)
#pragma unroll
        for (int nf = 0; nf < 8; nf++)
#pragma unroll
            for (int rg = 0; rg < 4; rg++) {
                int m = mwave + mf * 16 + quad * 4 + rg;
                if (m < NN) {
                    float v = fmaxf(acc[mf][nf][rg] + bs[nf], 0.f);
                    if (STATS) { sn[nf] += v; qn[nf] += v * v; }
                    C[(size_t)m * 128 + nf * 16 + ln] = f2bf(v);
                }
            }

    if (STATS) {
#pragma unroll
        for (int nf = 0; nf < 8; nf++) {
            float s = sn[nf], q = qn[nf];
            s += __shfl_xor(s, 16); s += __shfl_xor(s, 32);
            q += __shfl_xor(q, 16); q += __shfl_xor(q, 32);
            if (quad == 0) {
                unsafeAtomicAdd(&bnsum[nf * 16 + ln], s);
                unsafeAtomicAdd(&bnsum[128 + nf * 16 + ln], q);
            }
        }
    }
}

__global__ __launch_bounds__(128) void k_bn_final(const float* __restrict__ sums,
                                                  const float* __restrict__ gamma,
                                                  const float* __restrict__ beta,
                                                  float* __restrict__ bnp) {
    int c = threadIdx.x;
    if (c < D) {
        float mean = sums[c] / (float)NN;
        float var = sums[D + c] / (float)NN - mean * mean;
        float sc = gamma[c] * rsqrtf(var + BN_EPS);
        bnp[c] = sc;
        bnp[D + c] = beta[c] - mean * sc;
    }
}

// ---------------- final: out = relu(BN(R2) @ l1W + l1b) @ l2W + l2b ----------------
__global__ __launch_bounds__(256) void k_final(const unsigned short* __restrict__ R2,
                                               const float* __restrict__ bnp,
                                               const unsigned short* __restrict__ Wt3,
                                               const float* __restrict__ l1b,
                                               const float* __restrict__ l2W,
                                               const float* __restrict__ l2b,
                                               float* __restrict__ out) {
    int tid = threadIdx.x;
    int w = tid >> 6, lane = tid & 63;
    int ln = lane & 15, quad = lane >> 4;
    int mwave = blockIdx.x * 256 + w * 64;

    f32x4 acc[4][8];
#pragma unroll
    for (int a = 0; a < 4; a++)
#pragma unroll
        for (int b = 0; b < 8; b++) acc[a][b] = (f32x4){0.f, 0.f, 0.f, 0.f};

    size_t arow[4];
#pragma unroll
    for (int mf = 0; mf < 4; mf++) {
        int m = mwave + mf * 16 + ln;
        arow[mf] = (size_t)min(m, NN - 1) * 128;
    }
    size_t brow[8];
#pragma unroll
    for (int nf = 0; nf < 8; nf++) brow[nf] = (size_t)(nf * 16 + ln) * 128;

    for (int k0 = 0; k0 < 128; k0 += 32) {
        int kof = k0 + quad * 8;
        float4 scA = *(const float4*)(bnp + kof);
        float4 scB = *(const float4*)(bnp + kof + 4);
        float4 shA = *(const float4*)(bnp + 128 + kof);
        float4 shB = *(const float4*)(bnp + 128 + kof + 4);
        float scv[8] = {scA.x, scA.y, scA.z, scA.w, scB.x, scB.y, scB.z, scB.w};
        float shv[8] = {shA.x, shA.y, shA.z, shA.w, shB.x, shB.y, shB.z, shB.w};
        short8 af[4], bf[8];
#pragma unroll
        for (int mf = 0; mf < 4; mf++) {
            short8 rv = *(const short8*)(R2 + arow[mf] + kof);
            unsigned short ab[8];
#pragma unroll
            for (int j = 0; j < 8; j++)
                ab[j] = f2bf(bf2f((unsigned short)rv[j]) * scv[j] + shv[j]);
            af[mf] = *(short8*)ab;
        }
#pragma unroll
        for (int nf = 0; nf < 8; nf++) bf[nf] = *(const short8*)(Wt3 + brow[nf] + kof);
#pragma unroll
        for (int mf = 0; mf < 4; mf++)
#pragma unroll
            for (int nf = 0; nf < 8; nf++)
                acc[mf][nf] = __builtin_amdgcn_mfma_f32_16x16x32_bf16(af[mf], bf[nf], acc[mf][nf], 0, 0, 0);
    }

    float b1v[8], w0[8], w1[8];
#pragma unroll
    for (int nf = 0; nf < 8; nf++) {
        int n = nf * 16 + ln;
        b1v[nf] = l1b[n];
        w0[nf] = l2W[n * 2];
        w1[nf] = l2W[n * 2 + 1];
    }
    float ob0 = l2b[0], ob1 = l2b[1];
#pragma unroll
    for (int mf = 0; mf < 4; mf++)
#pragma unroll
        for (int rg = 0; rg < 4; rg++) {
            float p0 = 0.f, p1 = 0.f;
#pragma unroll
            for (int nf = 0; nf < 8; nf++) {
                float y = fmaxf(acc[mf][nf][rg] + b1v[nf], 0.f);
                p0 += y * w0[nf];
                p1 += y * w1[nf];
            }
            p0 += __shfl_xor(p0, 1); p0 += __shfl_xor(p0, 2);
            p0 += __shfl_xor(p0, 4); p0 += __shfl_xor(p0, 8);
            p1 += __shfl_xor(p1, 1); p1 += __shfl_xor(p1, 2);
            p1 += __shfl_xor(p1, 4); p1 += __shfl_xor(p1, 8);
            int m = mwave + mf * 16 + quad * 4 + rg;
            if (ln == 0 && m < NN) {
                out[(size_t)m * 2 + 0] = p0 + ob0;
                out[(size_t)m * 2 + 1] = p1 + ob1;
            }
        }
}

extern "C" void kernel_launch(void* const* d_in, const int* in_sizes, int n_in,
                              void* d_out, int out_size, void* d_ws, size_t ws_size,
                              hipStream_t stream) {
    const float* x = (const float*)d_in[0];
    const int* ei = (const int*)d_in[1];
    const float* W1 = (const float*)d_in[2];
    const float* b1 = (const float*)d_in[3];
    const float* W2 = (const float*)d_in[4];
    const float* b2 = (const float*)d_in[5];
    const float* gamma = (const float*)d_in[6];
    const float* beta = (const float*)d_in[7];
    const float* l1W = (const float*)d_in[8];
    const float* l1b = (const float*)d_in[9];
    const float* l2W = (const float*)d_in[10];
    const float* l2b = (const float*)d_in[11];
    float* out = (float*)d_out;

    char* ws = (char*)d_ws;
    size_t off = 0;
    auto alloc = [&](size_t bytes) {
        void* p = ws + off;
        off += (bytes + 255) & ~(size_t)255;
        return p;
    };
    float* dinv = (float*)alloc((size_t)NREL * NN * sizeof(float));
    int* rstart = (int*)alloc((size_t)NREL * NN * sizeof(int));
    int* rend = (int*)alloc((size_t)NREL * NN * sizeof(int));
    unsigned short* csr = (unsigned short*)alloc((size_t)NBK * BCAP * 2);            // 4.8 MB
    unsigned short* xb = (unsigned short*)alloc((size_t)NN * D * 2);                 // 12.8 MB
    unsigned short* Acat = (unsigned short*)alloc((size_t)NN * 512 * 2);             // 51.2 MB
    unsigned short* h1b = (unsigned short*)alloc((size_t)NN * D * 2);                // 12.8 MB
    unsigned short* R2b = (unsigned short*)alloc((size_t)NN * D * 2);                // 12.8 MB
    unsigned short* Wt1 = (unsigned short*)alloc(128 * 512 * 2);
    unsigned short* Wt2 = (unsigned short*)alloc(128 * 512 * 2);
    unsigned short* Wt3 = (unsigned short*)alloc(128 * 128 * 2);
    float* bs1 = (float*)alloc(128 * sizeof(float));
    float* bs2 = (float*)alloc(128 * sizeof(float));
    float* bnsum = (float*)alloc(256 * sizeof(float));
    float* bnp = (float*)alloc(256 * sizeof(float));

    k_zero<<<1, 256, 0, stream>>>((int*)bnsum, 256);
    k_prep<<<321, 256, 0, stream>>>(W1, W2, l1W, b1, b2, Wt1, Wt2, Wt3, bs1, bs2);
    k_cast<<<(NN * D / 4 + 255) / 256, 256, 0, stream>>>(x, xb);
    k_build<<<NBK, 512, 0, stream>>>(ei, csr, rstart, rend, dinv);

    dim3 agrid((NN + 3) / 4, NREL);
    // layer 1: aggregate x per relation -> Acat (concat), then one K=512 GEMM
    k_agg<<<agrid, 256, 0, stream>>>(xb, csr, rstart, rend, dinv, Acat);
    k_mm<512, false><<<(NN + 255) / 256, 256, 0, stream>>>(Acat, Wt1, bs1, h1b, nullptr);
    // layer 2
    k_agg<<<agrid, 256, 0, stream>>>(h1b, csr, rstart, rend, dinv, Acat);
    k_mm<512, true><<<(NN + 255) / 256, 256, 0, stream>>>(Acat, Wt2, bs2, R2b, bnsum);
    // BN params + fused MLP head
    k_bn_final<<<1, 128, 0, stream>>>(bnsum, gamma, beta, bnp);
    k_final<<<(NN + 255) / 256, 256, 0, stream>>>(R2b, bnp, Wt3, l1b, l2W, l2b, out);
}

// Round 5
// 445.129 us; speedup vs baseline: 8.5048x; 1.3995x over previous
//
#include <hip/hip_runtime.h>
#include <math.h>

#define NN 50000
#define NE 500000
#define NREL 4
#define D 128
#define RSZ 512                 // dst-range size (one bin)
#define NRANGE 98               // ceil(NN/512)
#define NBK (NREL * NRANGE)     // 392 sort blocks
#define BCAP 6144               // per-(range,rel) csr capacity (mean 5120, +14 sigma)
#define NCH 128                 // edge chunks per relation
#define CH 3907                 // edges per chunk (128*3907 >= 500000)
#define FCAP 96                 // frag capacity per (chunk,bin): mean 40, +9 sigma
static constexpr float BN_EPS = 1e-5f;

typedef __attribute__((ext_vector_type(8))) short short8;
typedef __attribute__((ext_vector_type(4))) float f32x4;

__device__ __forceinline__ float bf2f(unsigned short u) {
    return __uint_as_float(((unsigned)u) << 16);
}
__device__ __forceinline__ unsigned short f2bf(float f) {  // RTNE
    unsigned x = __float_as_uint(f);
    return (unsigned short)((x + 0x7FFFu + ((x >> 16) & 1u)) >> 16);
}

// ---------------- utility ----------------
__global__ __launch_bounds__(256) void k_zero(int* __restrict__ p, int n) {
    int i = blockIdx.x * blockDim.x + threadIdx.x;
    if (i < n) p[i] = 0;
}

// ---------------- pass A: bin edges into (chunk, range) fragment windows ----------------
// packed = src | dstlocal<<16 (src<50000 fits 16 bits, dstlocal 9 bits)
__global__ __launch_bounds__(256) void k_bin(const int* __restrict__ ei,
                                             int* __restrict__ frag,
                                             int* __restrict__ cntg) {
    int c = blockIdx.x, r = blockIdx.y;
    const int* srcp = ei + r * 2 * NE;
    const int* dstp = srcp + NE;
    __shared__ int bins[NRANGE * FCAP];  // 37.6 KB
    __shared__ int cnt[NRANGE];
    int tid = threadIdx.x;
    for (int i = tid; i < NRANGE; i += 256) cnt[i] = 0;
    __syncthreads();
    int e0 = c * CH, e1 = min(e0 + CH, NE);
    for (int e = e0 + tid; e < e1; e += 256) {
        int d = dstp[e];
        int s = srcp[e];
        int q = d >> 9;
        int pos = atomicAdd(&cnt[q], 1);
        if (pos < FCAP) bins[q * FCAP + pos] = s | ((d & 511) << 16);
    }
    __syncthreads();
    int w = tid >> 6, lane = tid & 63;
    for (int q = w; q < NRANGE; q += 4) {
        int k = min(cnt[q], FCAP);
        int gbase = ((r * NRANGE + q) * NCH + c) * FCAP;
        for (int i = lane; i < k; i += 64) frag[gbase + i] = bins[q * FCAP + i];
    }
    for (int q = tid; q < NRANGE; q += 256) cntg[(r * NRANGE + q) * NCH + c] = min(cnt[q], FCAP);
}

// ---------------- pass B: per (range, rel) counting-sort into CSR ----------------
__global__ __launch_bounds__(512) void k_sortb(const int* __restrict__ frag,
                                               const int* __restrict__ cntg,
                                               unsigned short* __restrict__ csr,
                                               int* __restrict__ rstart,
                                               int* __restrict__ rend,
                                               float* __restrict__ dinv) {
    int q = blockIdx.x, r = blockIdx.y;
    int blk = r * NRANGE + q;
    int n0 = q * RSZ;
    int nrows = min(RSZ, NN - n0);
    __shared__ int cnts[NCH], cbase[NCH];
    __shared__ int stage[BCAP];          // 24 KB
    __shared__ unsigned short csr_s[BCAP];
    __shared__ int hist[RSZ], off[RSZ], cnt2[RSZ];
    int tid = threadIdx.x;
    hist[tid] = 0;
    cnt2[tid] = 0;
    if (tid < NCH) cnts[tid] = cntg[blk * NCH + tid];
    __syncthreads();
    // exclusive scan of 128 chunk counts
    if (tid < NCH) cbase[tid] = cnts[tid];
    __syncthreads();
    for (int d = 1; d < NCH; d <<= 1) {
        int t = 0;
        if (tid < NCH && tid >= d) t = cbase[tid - d];
        __syncthreads();
        if (tid < NCH) cbase[tid] += t;
        __syncthreads();
    }
    if (tid < NCH) cbase[tid] -= cnts[tid];
    __syncthreads();
    int tot = cbase[NCH - 1] + cnts[NCH - 1];
    // parallel gather of all 128 fragment windows (4 threads per chunk)
    {
        int g = tid >> 2, l = tid & 3;
        int k = cnts[g], cb = cbase[g];
        int gbase = (blk * NCH + g) * FCAP;
        for (int i = l; i < k; i += 4)
            if (cb + i < BCAP) stage[cb + i] = frag[gbase + i];
    }
    __syncthreads();
    if (tot > BCAP) tot = BCAP;
    // histogram over dst-local
    for (int i = tid; i < tot; i += 512) atomicAdd(&hist[(stage[i] >> 16) & 511], 1);
    __syncthreads();
    int h = hist[tid];
    if (tid < nrows) dinv[r * NN + n0 + tid] = rsqrtf((float)(h + 1));  // +1 self loop
    // inclusive scan -> exclusive offsets
    off[tid] = h;
    __syncthreads();
    for (int d = 1; d < RSZ; d <<= 1) {
        int t = (tid >= d) ? off[tid - d] : 0;
        __syncthreads();
        off[tid] += t;
        __syncthreads();
    }
    int excl = off[tid] - h;
    __syncthreads();
    off[tid] = excl;
    int base = blk * BCAP;
    if (tid < nrows) {
        rstart[r * NN + n0 + tid] = base + excl;
        rend[r * NN + n0 + tid] = base + excl + h;
    }
    __syncthreads();
    // counting-sort into LDS
    for (int i = tid; i < tot; i += 512) {
        int v = stage[i];
        int dl = (v >> 16) & 511;
        int p = atomicAdd(&cnt2[dl], 1);
        csr_s[off[dl] + p] = (unsigned short)(v & 0xFFFF);
    }
    __syncthreads();
    // coalesced block-private write-out
    for (int i = tid; i < tot; i += 512) csr[base + i] = csr_s[i];
}

// ---------------- fp32 -> bf16 cast of x ----------------
__global__ __launch_bounds__(256) void k_cast(const float* __restrict__ x, unsigned short* __restrict__ xb) {
    int i = blockIdx.x * 256 + threadIdx.x;
    if (i * 4 >= NN * D) return;
    float4 v = *(const float4*)(x + (size_t)i * 4);
    unsigned short u[4] = {f2bf(v.x), f2bf(v.y), f2bf(v.z), f2bf(v.w)};
    *(ushort4*)(xb + (size_t)i * 4) = *(ushort4*)u;
}

// ---------------- weight prep: bf16 transposed weights + summed biases ----------------
__global__ __launch_bounds__(256) void k_prep(const float* __restrict__ W1, const float* __restrict__ W2,
                                              const float* __restrict__ l1W, const float* __restrict__ b1,
                                              const float* __restrict__ b2, unsigned short* __restrict__ Wt1,
                                              unsigned short* __restrict__ Wt2, unsigned short* __restrict__ Wt3,
                                              float* __restrict__ bs1, float* __restrict__ bs2) {
    int blk = blockIdx.x, tid = threadIdx.x;
    if (blk < 256) {
        int i = blk * 256 + tid;         // [0, 65536)
        int kk = i & 511, n = i >> 9;    // coalesced stores along kk
        Wt1[n * 512 + kk] = f2bf(W1[kk * 128 + n]);
        Wt2[n * 512 + kk] = f2bf(W2[kk * 128 + n]);
    } else if (blk < 320) {
        int i = (blk - 256) * 256 + tid; // [0, 16384)
        int kk = i & 127, n = i >> 7;
        Wt3[n * 128 + kk] = f2bf(l1W[kk * 128 + n]);
    } else if (tid < 128) {
        bs1[tid] = b1[tid] + b1[128 + tid] + b1[256 + tid] + b1[384 + tid];
        bs2[tid] = b2[tid] + b2[128 + tid] + b2[256 + tid] + b2[384 + tid];
    }
}

// ---------------- per-(node,relation) gather aggregation, 4-way unrolled ----------------
// Acat[n][r*128+c] = dinv[n] * ( sum_{src->n} in[src][c]*dinv[src] + in[n][c]*dinv[n] )
__global__ __launch_bounds__(256) void k_agg(const unsigned short* __restrict__ in,  // bf16 [NN][128]
                                             const unsigned short* __restrict__ csr,
                                             const int* __restrict__ rstart,
                                             const int* __restrict__ rend,
                                             const float* __restrict__ dinv,         // [NREL][NN]
                                             unsigned short* __restrict__ Acat) {    // bf16 [NN][512]
    int r = blockIdx.y;
    int wave = threadIdx.x >> 6, lane = threadIdx.x & 63;
    int n = blockIdx.x * 4 + wave;
    if (n >= NN) return;
    const float* dv = dinv + r * NN;
    int start = rstart[r * NN + n], end = rend[r * NN + n];
    const ushort2* in2 = (const ushort2*)in;
    float ax = 0.f, ay = 0.f;
    int e = start;
    for (; e + 4 <= end; e += 4) {
        int s0 = csr[e], s1 = csr[e + 1], s2 = csr[e + 2], s3 = csr[e + 3];
        float w0 = dv[s0], w1 = dv[s1], w2 = dv[s2], w3 = dv[s3];
        ushort2 u0 = in2[s0 * 64 + lane];
        ushort2 u1 = in2[s1 * 64 + lane];
        ushort2 u2 = in2[s2 * 64 + lane];
        ushort2 u3 = in2[s3 * 64 + lane];
        ax = fmaf(bf2f(u0.x), w0, ax); ay = fmaf(bf2f(u0.y), w0, ay);
        ax = fmaf(bf2f(u1.x), w1, ax); ay = fmaf(bf2f(u1.y), w1, ay);
        ax = fmaf(bf2f(u2.x), w2, ax); ay = fmaf(bf2f(u2.y), w2, ay);
        ax = fmaf(bf2f(u3.x), w3, ax); ay = fmaf(bf2f(u3.y), w3, ay);
    }
    for (; e < end; e++) {
        int s = csr[e];
        float w = dv[s];
        ushort2 u = in2[s * 64 + lane];
        ax = fmaf(bf2f(u.x), w, ax);
        ay = fmaf(bf2f(u.y), w, ay);
    }
    float wn = dv[n];
    ushort2 us = in2[n * 64 + lane];
    ax = fmaf(bf2f(us.x), wn, ax);
    ay = fmaf(bf2f(us.y), wn, ay);
    ushort2 o;
    o.x = f2bf(wn * ax);
    o.y = f2bf(wn * ay);
    *(ushort2*)(Acat + (size_t)n * 512 + r * 128 + 2 * lane) = o;
}

// ---------------- MFMA GEMM: C[NN][128] = relu(A[NN][K] @ W[K][128] + bias) (bf16 in/out) ----------------
template <int K, bool STATS>
__global__ __launch_bounds__(256) void k_mm(const unsigned short* __restrict__ A,
                                            const unsigned short* __restrict__ Bt,
                                            const float* __restrict__ bias,
                                            unsigned short* __restrict__ C,
                                            float* __restrict__ bnsum) {
    int tid = threadIdx.x;
    int w = tid >> 6, lane = tid & 63;
    int ln = lane & 15, quad = lane >> 4;
    int mwave = blockIdx.x * 256 + w * 64;

    f32x4 acc[4][8];
#pragma unroll
    for (int a = 0; a < 4; a++)
#pragma unroll
        for (int b = 0; b < 8; b++) acc[a][b] = (f32x4){0.f, 0.f, 0.f, 0.f};

    size_t arow[4];
#pragma unroll
    for (int mf = 0; mf < 4; mf++) {
        int m = mwave + mf * 16 + ln;
        arow[mf] = (size_t)min(m, NN - 1) * K;  // clamp; garbage rows guarded at store
    }
    size_t brow[8];
#pragma unroll
    for (int nf = 0; nf < 8; nf++) brow[nf] = (size_t)(nf * 16 + ln) * K;

    for (int k0 = 0; k0 < K; k0 += 32) {
        int kof = k0 + quad * 8;
        short8 af[4], bf[8];
#pragma unroll
        for (int mf = 0; mf < 4; mf++) af[mf] = *(const short8*)(A + arow[mf] + kof);
#pragma unroll
        for (int nf = 0; nf < 8; nf++) bf[nf] = *(const short8*)(Bt + brow[nf] + kof);
#pragma unroll
        for (int mf = 0; mf < 4; mf++)
#pragma unroll
            for (int nf = 0; nf < 8; nf++)
                acc[mf][nf] = __builtin_amdgcn_mfma_f32_16x16x32_bf16(af[mf], bf[nf], acc[mf][nf], 0, 0, 0);
    }

    float bs[8];
#pragma unroll
    for (int nf = 0; nf < 8; nf++) bs[nf] = bias[nf * 16 + ln];
    float sn[8], qn[8];
#pragma unroll
    for (int nf = 0; nf < 8; nf++) { sn[nf] = 0.f; qn[nf] = 0.f; }

#pragma unroll
    for (int mf = 0; mf < 4; mf++)
#pragma unroll
        for (int nf = 0; nf < 8; nf++)
#pragma unroll
            for (int rg = 0; rg < 4; rg++) {
                int m = mwave + mf * 16 + quad * 4 + rg;
                if (m < NN) {
                    float v = fmaxf(acc[mf][nf][rg] + bs[nf], 0.f);
                    if (STATS) { sn[nf] += v; qn[nf] += v * v; }
                    C[(size_t)m * 128 + nf * 16 + ln] = f2bf(v);
                }
            }

    if (STATS) {
#pragma unroll
        for (int nf = 0; nf < 8; nf++) {
            float s = sn[nf], q = qn[nf];
            s += __shfl_xor(s, 16); s += __shfl_xor(s, 32);
            q += __shfl_xor(q, 16); q += __shfl_xor(q, 32);
            if (quad == 0) {
                unsafeAtomicAdd(&bnsum[nf * 16 + ln], s);
                unsafeAtomicAdd(&bnsum[128 + nf * 16 + ln], q);
            }
        }
    }
}

__global__ __launch_bounds__(128) void k_bn_final(const float* __restrict__ sums,
                                                  const float* __restrict__ gamma,
                                                  const float* __restrict__ beta,
                                                  float* __restrict__ bnp) {
    int c = threadIdx.x;
    if (c < D) {
        float mean = sums[c] / (float)NN;
        float var = sums[D + c] / (float)NN - mean * mean;
        float sc = gamma[c] * rsqrtf(var + BN_EPS);
        bnp[c] = sc;
        bnp[D + c] = beta[c] - mean * sc;
    }
}

// ---------------- final: out = relu(BN(R2) @ l1W + l1b) @ l2W + l2b ----------------
__global__ __launch_bounds__(256) void k_final(const unsigned short* __restrict__ R2,
                                               const float* __restrict__ bnp,
                                               const unsigned short* __restrict__ Wt3,
                                               const float* __restrict__ l1b,
                                               const float* __restrict__ l2W,
                                               const float* __restrict__ l2b,
                                               float* __restrict__ out) {
    int tid = threadIdx.x;
    int w = tid >> 6, lane = tid & 63;
    int ln = lane & 15, quad = lane >> 4;
    int mwave = blockIdx.x * 256 + w * 64;

    f32x4 acc[4][8];
#pragma unroll
    for (int a = 0; a < 4; a++)
#pragma unroll
        for (int b = 0; b < 8; b++) acc[a][b] = (f32x4){0.f, 0.f, 0.f, 0.f};

    size_t arow[4];
#pragma unroll
    for (int mf = 0; mf < 4; mf++) {
        int m = mwave + mf * 16 + ln;
        arow[mf] = (size_t)min(m, NN - 1) * 128;
    }
    size_t brow[8];
#pragma unroll
    for (int nf = 0; nf < 8; nf++) brow[nf] = (size_t)(nf * 16 + ln) * 128;

    for (int k0 = 0; k0 < 128; k0 += 32) {
        int kof = k0 + quad * 8;
        float4 scA = *(const float4*)(bnp + kof);
        float4 scB = *(const float4*)(bnp + kof + 4);
        float4 shA = *(const float4*)(bnp + 128 + kof);
        float4 shB = *(const float4*)(bnp + 128 + kof + 4);
        float scv[8] = {scA.x, scA.y, scA.z, scA.w, scB.x, scB.y, scB.z, scB.w};
        float shv[8] = {shA.x, shA.y, shA.z, shA.w, shB.x, shB.y, shB.z, shB.w};
        short8 af[4], bf[8];
#pragma unroll
        for (int mf = 0; mf < 4; mf++) {
            short8 rv = *(const short8*)(R2 + arow[mf] + kof);
            unsigned short ab[8];
#pragma unroll
            for (int j = 0; j < 8; j++)
                ab[j] = f2bf(bf2f((unsigned short)rv[j]) * scv[j] + shv[j]);
            af[mf] = *(short8*)ab;
        }
#pragma unroll
        for (int nf = 0; nf < 8; nf++) bf[nf] = *(const short8*)(Wt3 + brow[nf] + kof);
#pragma unroll
        for (int mf = 0; mf < 4; mf++)
#pragma unroll
            for (int nf = 0; nf < 8; nf++)
                acc[mf][nf] = __builtin_amdgcn_mfma_f32_16x16x32_bf16(af[mf], bf[nf], acc[mf][nf], 0, 0, 0);
    }

    float b1v[8], w0[8], w1[8];
#pragma unroll
    for (int nf = 0; nf < 8; nf++) {
        int n = nf * 16 + ln;
        b1v[nf] = l1b[n];
        w0[nf] = l2W[n * 2];
        w1[nf] = l2W[n * 2 + 1];
    }
    float ob0 = l2b[0], ob1 = l2b[1];
#pragma unroll
    for (int mf = 0; mf < 4; mf++)
#pragma unroll
        for (int rg = 0; rg < 4; rg++) {
            float p0 = 0.f, p1 = 0.f;
#pragma unroll
            for (int nf = 0; nf < 8; nf++) {
                float y = fmaxf(acc[mf][nf][rg] + b1v[nf], 0.f);
                p0 += y * w0[nf];
                p1 += y * w1[nf];
            }
            p0 += __shfl_xor(p0, 1); p0 += __shfl_xor(p0, 2);
            p0 += __shfl_xor(p0, 4); p0 += __shfl_xor(p0, 8);
            p1 += __shfl_xor(p1, 1); p1 += __shfl_xor(p1, 2);
            p1 += __shfl_xor(p1, 4); p1 += __shfl_xor(p1, 8);
            int m = mwave + mf * 16 + quad * 4 + rg;
            if (ln == 0 && m < NN) {
                out[(size_t)m * 2 + 0] = p0 + ob0;
                out[(size_t)m * 2 + 1] = p1 + ob1;
            }
        }
}

extern "C" void kernel_launch(void* const* d_in, const int* in_sizes, int n_in,
                              void* d_out, int out_size, void* d_ws, size_t ws_size,
                              hipStream_t stream) {
    const float* x = (const float*)d_in[0];
    const int* ei = (const int*)d_in[1];
    const float* W1 = (const float*)d_in[2];
    const float* b1 = (const float*)d_in[3];
    const float* W2 = (const float*)d_in[4];
    const float* b2 = (const float*)d_in[5];
    const float* gamma = (const float*)d_in[6];
    const float* beta = (const float*)d_in[7];
    const float* l1W = (const float*)d_in[8];
    const float* l1b = (const float*)d_in[9];
    const float* l2W = (const float*)d_in[10];
    const float* l2b = (const float*)d_in[11];
    float* out = (float*)d_out;

    char* ws = (char*)d_ws;
    size_t off = 0;
    auto alloc = [&](size_t bytes) {
        void* p = ws + off;
        off += (bytes + 255) & ~(size_t)255;
        return p;
    };
    float* dinv = (float*)alloc((size_t)NREL * NN * sizeof(float));
    int* rstart = (int*)alloc((size_t)NREL * NN * sizeof(int));
    int* rend = (int*)alloc((size_t)NREL * NN * sizeof(int));
    unsigned short* csr = (unsigned short*)alloc((size_t)NBK * BCAP * 2);            // 4.8 MB
    unsigned short* xb = (unsigned short*)alloc((size_t)NN * D * 2);                 // 12.8 MB
    unsigned short* Acat = (unsigned short*)alloc((size_t)NN * 512 * 2);             // 51.2 MB
    unsigned short* h1b = (unsigned short*)alloc((size_t)NN * D * 2);                // 12.8 MB
    unsigned short* R2b = (unsigned short*)alloc((size_t)NN * D * 2);                // 12.8 MB
    unsigned short* Wt1 = (unsigned short*)alloc(128 * 512 * 2);
    unsigned short* Wt2 = (unsigned short*)alloc(128 * 512 * 2);
    unsigned short* Wt3 = (unsigned short*)alloc(128 * 128 * 2);
    float* bs1 = (float*)alloc(128 * sizeof(float));
    float* bs2 = (float*)alloc(128 * sizeof(float));
    float* bnsum = (float*)alloc(256 * sizeof(float));
    float* bnp = (float*)alloc(256 * sizeof(float));

    // frag/cntg alias Acat's storage (dead until k_agg writes it, after k_sortb completes)
    int* frag = (int*)Acat;                                       // 19.3 MB
    int* cntg = frag + (size_t)NREL * NRANGE * NCH * FCAP;        // 0.2 MB

    k_zero<<<1, 256, 0, stream>>>((int*)bnsum, 256);
    k_prep<<<321, 256, 0, stream>>>(W1, W2, l1W, b1, b2, Wt1, Wt2, Wt3, bs1, bs2);
    k_cast<<<(NN * D / 4 + 255) / 256, 256, 0, stream>>>(x, xb);
    dim3 bgrid(NCH, NREL);
    k_bin<<<bgrid, 256, 0, stream>>>(ei, frag, cntg);
    dim3 sgrid(NRANGE, NREL);
    k_sortb<<<sgrid, 512, 0, stream>>>(frag, cntg, csr, rstart, rend, dinv);

    dim3 agrid((NN + 3) / 4, NREL);
    // layer 1: aggregate x per relation -> Acat (concat), then one K=512 GEMM
    k_agg<<<agrid, 256, 0, stream>>>(xb, csr, rstart, rend, dinv, Acat);
    k_mm<512, false><<<(NN + 255) / 256, 256, 0, stream>>>(Acat, Wt1, bs1, h1b, nullptr);
    // layer 2
    k_agg<<<agrid, 256, 0, stream>>>(h1b, csr, rstart, rend, dinv, Acat);
    k_mm<512, true><<<(NN + 255) / 256, 256, 0, stream>>>(Acat, Wt2, bs2, R2b, bnsum);
    // BN params + fused MLP head
    k_bn_final<<<1, 128, 0, stream>>>(bnsum, gamma, beta, bnp);
    k_final<<<(NN + 255) / 256, 256, 0, stream>>>(R2b, bnp, Wt3, l1b, l2W, l2b, out);
}